// Round 1
// baseline (2127.246 us; speedup 1.0000x reference)
//
#include <hip/hip_runtime.h>
#include <math.h>

#define S_LEN 4096
#define B_SZ 2
#define DM 512
#define NH 8
#define DH 64
#define WINDOW 256

// C[m,n] = sum_k A[m*lda + k] * W[n*K + k] + bias[n]
// M, N, K all multiples of 32 (8192 / 1536|512 / 512) -> no bounds checks.
__global__ __launch_bounds__(1024) void gemm_bias(
    const float* __restrict__ A, const float* __restrict__ W,
    const float* __restrict__ bias, float* __restrict__ C,
    int M, int N, int K, int lda) {
  __shared__ float As[32][33];
  __shared__ float Ws[32][33];
  const int tx = threadIdx.x, ty = threadIdx.y;
  const int m = blockIdx.y * 32 + ty;
  const int n = blockIdx.x * 32 + tx;
  float acc = 0.f;
  for (int k0 = 0; k0 < K; k0 += 32) {
    As[ty][tx] = A[(size_t)m * lda + k0 + tx];
    Ws[ty][tx] = W[(size_t)(blockIdx.x * 32 + ty) * K + k0 + tx];
    __syncthreads();
#pragma unroll
    for (int kk = 0; kk < 32; ++kk)
      acc += As[ty][kk] * Ws[tx][kk];
    __syncthreads();
  }
  C[(size_t)m * N + n] = acc + bias[n];
}

// One 64-lane wave per (b, i, h). Lane = head dim. Online softmax over the
// sliding window. Writes attention output into the q-slot of qkv in place
// (only this wave ever reads its own q row, so this is race-free).
__global__ __launch_bounds__(256) void attn_kernel(float* __restrict__ qkv) {
  const int gid = blockIdx.x * blockDim.x + threadIdx.x;
  const int wave = gid >> 6;
  const int lane = gid & 63;
  const int h = wave & (NH - 1);
  const int rest = wave >> 3;          // NH == 8
  const int i = rest & (S_LEN - 1);    // S_LEN == 4096
  const int b = rest >> 12;
  float* base = qkv + (size_t)b * S_LEN * (3 * DM);
  const float qd = base[(size_t)i * (3 * DM) + h * DH + lane] * 0.125f; // 1/sqrt(64)

  int j0 = i - WINDOW;
  if (j0 < 0) j0 = 0;

  float m = -1e30f, l = 0.f, o = 0.f;
  for (int j = j0; j <= i; ++j) {
    const float* krow = base + (size_t)j * (3 * DM) + DM + h * DH;
    float s = qd * krow[lane];
#pragma unroll
    for (int off = 32; off >= 1; off >>= 1) s += __shfl_xor(s, off, 64);
    const float mn = fmaxf(m, s);
    const float sc = __expf(m - mn);
    const float p = __expf(s - mn);
    const float* vrow = base + (size_t)j * (3 * DM) + 2 * DM + h * DH;
    o = o * sc + p * vrow[lane];
    l = l * sc + p;
    m = mn;
  }
  base[(size_t)i * (3 * DM) + h * DH + lane] = o / l;
}

extern "C" void kernel_launch(void* const* d_in, const int* in_sizes, int n_in,
                              void* d_out, int out_size, void* d_ws, size_t ws_size,
                              hipStream_t stream) {
  const float* x     = (const float*)d_in[0];
  const float* qkv_w = (const float*)d_in[1];
  const float* qkv_b = (const float*)d_in[2];
  const float* out_w = (const float*)d_in[3];
  const float* out_b = (const float*)d_in[4];
  float* out = (float*)d_out;
  float* qkv = (float*)d_ws;          // (B, S, 3, NH, DH) fp32 = 50.3 MB

  const int M = B_SZ * S_LEN;         // 8192

  dim3 blk(32, 32);
  // qkv = x @ qkv_w.T + qkv_b   -> (8192, 1536)
  gemm_bias<<<dim3((3 * DM) / 32, M / 32), blk, 0, stream>>>(
      x, qkv_w, qkv_b, qkv, M, 3 * DM, DM, DM);

  // attention in place (out -> q slot)
  const int total_threads = M * NH * 64;
  attn_kernel<<<total_threads / 256, 256, 0, stream>>>(qkv);

  // out = attn @ out_w.T + out_b, attn rows have stride 1536 (q slot)
  gemm_bias<<<dim3(DM / 32, M / 32), blk, 0, stream>>>(
      qkv, out_w, out_b, out, M, DM, DM, 3 * DM);
}

// Round 2
// 275.175 us; speedup vs baseline: 7.7305x; 7.7305x over previous
//
#include <hip/hip_runtime.h>
#include <math.h>

#define S_LEN 4096
#define BATCH 2
#define DM 512
#define NH 8
#define DH 64
#define WINDOW 256
#define QKV_LD (3 * DM)  // 1536

typedef __bf16 bf16x8 __attribute__((ext_vector_type(8)));
typedef float f32x4 __attribute__((ext_vector_type(4)));
typedef unsigned short u16x4 __attribute__((ext_vector_type(4)));

__device__ __forceinline__ unsigned short f2bf(float f) {
  unsigned int u = __float_as_uint(f);
  u += 0x7fffu + ((u >> 16) & 1u);  // RNE
  return (unsigned short)(u >> 16);
}

// C[m][n] = sum_k A[m*lda+k] * W[n*K+k] + bias[n]; M%64==0, N%64==0, K%32==0.
// bf16 MFMA 16x16x32, 64x64 block tile, 4 waves of 32x32 (2x2 of 16x16).
__global__ __launch_bounds__(256) void gemm_bt_mfma(
    const float* __restrict__ A, const float* __restrict__ W,
    const float* __restrict__ bias, float* __restrict__ C,
    int M, int N, int K, int lda) {
  // 64 rows x 32 k, stride 40 bf16 (=80B, keeps 16B alignment, breaks bank aliasing)
  __shared__ __align__(16) unsigned short sA[64 * 40];
  __shared__ __align__(16) unsigned short sB[64 * 40];
  const int t = threadIdx.x;
  const int wave = t >> 6, lane = t & 63;
  const int wr = wave >> 1, wc = wave & 1;
  const int quad = lane >> 4, l16 = lane & 15;
  const int m0 = blockIdx.y * 64, n0 = blockIdx.x * 64;

  f32x4 acc[2][2] = {};

  const int srow = t >> 3;  // 0..31, +32 on second pass
  const int sc4 = t & 7;    // float4 index within a 32-float row

  for (int k0 = 0; k0 < K; k0 += 32) {
#pragma unroll
    for (int s = 0; s < 2; ++s) {
      const int row = srow + s * 32;
      const float4 av = *(const float4*)(A + (size_t)(m0 + row) * lda + k0 + sc4 * 4);
      u16x4 ua;
      ua[0] = f2bf(av.x); ua[1] = f2bf(av.y); ua[2] = f2bf(av.z); ua[3] = f2bf(av.w);
      *(u16x4*)&sA[row * 40 + sc4 * 4] = ua;
      const float4 wv = *(const float4*)(W + (size_t)(n0 + row) * K + k0 + sc4 * 4);
      u16x4 ub;
      ub[0] = f2bf(wv.x); ub[1] = f2bf(wv.y); ub[2] = f2bf(wv.z); ub[3] = f2bf(wv.w);
      *(u16x4*)&sB[row * 40 + sc4 * 4] = ub;
    }
    __syncthreads();
    bf16x8 af[2], bfr[2];
#pragma unroll
    for (int ti = 0; ti < 2; ++ti)
      af[ti] = *(const bf16x8*)&sA[(wr * 32 + ti * 16 + l16) * 40 + quad * 8];
#pragma unroll
    for (int tj = 0; tj < 2; ++tj)
      bfr[tj] = *(const bf16x8*)&sB[(wc * 32 + tj * 16 + l16) * 40 + quad * 8];
#pragma unroll
    for (int ti = 0; ti < 2; ++ti)
#pragma unroll
      for (int tj = 0; tj < 2; ++tj)
        acc[ti][tj] = __builtin_amdgcn_mfma_f32_16x16x32_bf16(af[ti], bfr[tj], acc[ti][tj], 0, 0, 0);
    __syncthreads();
  }

#pragma unroll
  for (int tj = 0; tj < 2; ++tj) {
    const int gc = n0 + wc * 32 + tj * 16 + l16;
    const float bv = bias[gc];
#pragma unroll
    for (int ti = 0; ti < 2; ++ti) {
      const int gr0 = m0 + wr * 32 + ti * 16 + quad * 4;
#pragma unroll
      for (int rg = 0; rg < 4; ++rg)
        C[(size_t)(gr0 + rg) * N + gc] = acc[ti][tj][rg] + bv;
    }
  }
}

// Flash-tiled sliding-window attention, fp32. One WG (256 thr) per (b,h,64-query tile).
// Window [i-256, i] => keys [q0-256, q0+63] = five 64-aligned chunks (skip negatives).
// Thread (ty=t>>4, tx=t&15) owns q-rows ty*4+{0..3}, k-cols/d-cols tx*4+{0..3}.
// Output written in place into the q-slot of qkv.
__global__ __launch_bounds__(256) void attn_tiled(float* __restrict__ qkv) {
  __shared__ float Qs[64 * 65];
  __shared__ float Ks[64 * 65];  // reused as P after scores are consumed
  __shared__ float Vs[64 * 65];
  const int t = threadIdx.x;
  const int tx = t & 15, ty = t >> 4;
  const int q0 = blockIdx.x * 64;
  const int h = blockIdx.y;
  const int b = blockIdx.z;
  float* base = qkv + (size_t)b * S_LEN * QKV_LD;

  // load Q tile (64 rows x 64 dims)
#pragma unroll
  for (int s = 0; s < 4; ++s) {
    const int f = t + 256 * s;
    const int row = f >> 4, c4 = f & 15;
    const float4 v = *(const float4*)(base + (size_t)(q0 + row) * QKV_LD + h * DH + c4 * 4);
    Qs[row * 65 + c4 * 4 + 0] = v.x;
    Qs[row * 65 + c4 * 4 + 1] = v.y;
    Qs[row * 65 + c4 * 4 + 2] = v.z;
    Qs[row * 65 + c4 * 4 + 3] = v.w;
  }

  float m_[4], l_[4], O[4][4] = {};
#pragma unroll
  for (int i = 0; i < 4; ++i) { m_[i] = -1e30f; l_[i] = 0.f; }

  for (int c = 0; c < 5; ++c) {
    const int c0 = q0 - WINDOW + c * 64;
    if (c0 < 0) continue;  // block-uniform
    __syncthreads();       // prior chunk's P/V reads done before overwrite
#pragma unroll
    for (int s = 0; s < 4; ++s) {
      const int f = t + 256 * s;
      const int row = f >> 4, c4 = f & 15;
      const float* kp = base + (size_t)(c0 + row) * QKV_LD + DM + h * DH + c4 * 4;
      const float4 kv = *(const float4*)kp;
      Ks[row * 65 + c4 * 4 + 0] = kv.x;
      Ks[row * 65 + c4 * 4 + 1] = kv.y;
      Ks[row * 65 + c4 * 4 + 2] = kv.z;
      Ks[row * 65 + c4 * 4 + 3] = kv.w;
      const float4 vv = *(const float4*)(kp + DM);
      Vs[row * 65 + c4 * 4 + 0] = vv.x;
      Vs[row * 65 + c4 * 4 + 1] = vv.y;
      Vs[row * 65 + c4 * 4 + 2] = vv.z;
      Vs[row * 65 + c4 * 4 + 3] = vv.w;
    }
    __syncthreads();

    float sc[4][4] = {};
    for (int kk = 0; kk < 64; ++kk) {
      float qv[4], kv[4];
#pragma unroll
      for (int a = 0; a < 4; ++a) qv[a] = Qs[(ty * 4 + a) * 65 + kk];
#pragma unroll
      for (int a = 0; a < 4; ++a) kv[a] = Ks[(tx * 4 + a) * 65 + kk];
#pragma unroll
      for (int qi = 0; qi < 4; ++qi)
#pragma unroll
        for (int kj = 0; kj < 4; ++kj) sc[qi][kj] += qv[qi] * kv[kj];
    }
    // scale + mask
#pragma unroll
    for (int qi = 0; qi < 4; ++qi) {
      const int i = q0 + ty * 4 + qi;
#pragma unroll
      for (int kj = 0; kj < 4; ++kj) {
        const int j = c0 + tx * 4 + kj;
        const bool ok = (j <= i) && (j >= i - WINDOW);
        sc[qi][kj] = ok ? sc[qi][kj] * 0.125f : -1e30f;
      }
    }
    // chunk row max (reduce over tx = lane bits 0..3)
    float cmax[4], csum[4], alpha[4];
#pragma unroll
    for (int qi = 0; qi < 4; ++qi)
      cmax[qi] = fmaxf(fmaxf(sc[qi][0], sc[qi][1]), fmaxf(sc[qi][2], sc[qi][3]));
#pragma unroll
    for (int off = 1; off <= 8; off <<= 1)
#pragma unroll
      for (int qi = 0; qi < 4; ++qi)
        cmax[qi] = fmaxf(cmax[qi], __shfl_xor(cmax[qi], off));
#pragma unroll
    for (int qi = 0; qi < 4; ++qi) {
      const float mn = fmaxf(m_[qi], cmax[qi]);
      alpha[qi] = __expf(m_[qi] - mn);
      m_[qi] = mn;
      float su = 0.f;
#pragma unroll
      for (int kj = 0; kj < 4; ++kj) {
        const float p = __expf(sc[qi][kj] - mn);
        sc[qi][kj] = p;
        su += p;
      }
      csum[qi] = su;
    }
#pragma unroll
    for (int off = 1; off <= 8; off <<= 1)
#pragma unroll
      for (int qi = 0; qi < 4; ++qi) csum[qi] += __shfl_xor(csum[qi], off);
#pragma unroll
    for (int qi = 0; qi < 4; ++qi) {
      l_[qi] = l_[qi] * alpha[qi] + csum[qi];
#pragma unroll
      for (int di = 0; di < 4; ++di) O[qi][di] *= alpha[qi];
    }
    __syncthreads();  // all K reads done; Ks becomes P
#pragma unroll
    for (int qi = 0; qi < 4; ++qi)
#pragma unroll
      for (int kj = 0; kj < 4; ++kj)
        Ks[(ty * 4 + qi) * 65 + tx * 4 + kj] = sc[qi][kj];
    __syncthreads();
    for (int jj = 0; jj < 64; ++jj) {
      float pv[4], vv[4];
#pragma unroll
      for (int a = 0; a < 4; ++a) pv[a] = Ks[(ty * 4 + a) * 65 + jj];
#pragma unroll
      for (int a = 0; a < 4; ++a) vv[a] = Vs[jj * 65 + tx * 4 + a];
#pragma unroll
      for (int qi = 0; qi < 4; ++qi)
#pragma unroll
        for (int di = 0; di < 4; ++di) O[qi][di] += pv[qi] * vv[di];
    }
  }

#pragma unroll
  for (int qi = 0; qi < 4; ++qi) {
    const float inv = 1.f / l_[qi];
    float4 o4;
    o4.x = O[qi][0] * inv;
    o4.y = O[qi][1] * inv;
    o4.z = O[qi][2] * inv;
    o4.w = O[qi][3] * inv;
    *(float4*)(base + (size_t)(q0 + ty * 4 + qi) * QKV_LD + h * DH + tx * 4) = o4;
  }
}

extern "C" void kernel_launch(void* const* d_in, const int* in_sizes, int n_in,
                              void* d_out, int out_size, void* d_ws, size_t ws_size,
                              hipStream_t stream) {
  const float* x = (const float*)d_in[0];
  const float* qkv_w = (const float*)d_in[1];
  const float* qkv_b = (const float*)d_in[2];
  const float* out_w = (const float*)d_in[3];
  const float* out_b = (const float*)d_in[4];
  float* out = (float*)d_out;
  float* qkv = (float*)d_ws;  // (B, S, 3, NH, DH) fp32 = 50.3 MB

  const int M = BATCH * S_LEN;  // 8192

  // qkv = x @ qkv_w.T + qkv_b -> (8192, 1536)
  gemm_bt_mfma<<<dim3((3 * DM) / 64, M / 64), 256, 0, stream>>>(
      x, qkv_w, qkv_b, qkv, M, 3 * DM, DM, DM);

  // attention in place (out -> q slot)
  attn_tiled<<<dim3(S_LEN / 64, NH, BATCH), 256, 0, stream>>>(qkv);

  // out = attn @ out_w.T + out_b; attn rows live in the q-slot, stride 1536
  gemm_bt_mfma<<<dim3(DM / 64, M / 64), 256, 0, stream>>>(
      qkv, out_w, out_b, out, M, DM, DM, QKV_LD);
}

// Round 4
// 150.908 us; speedup vs baseline: 14.0964x; 1.8235x over previous
//
#include <hip/hip_runtime.h>

#define S_LEN 4096
#define BATCH 2
#define DM 512
#define NH 8
#define DH 64
#define WINDOW 256

typedef __bf16 bf16x8 __attribute__((ext_vector_type(8)));
typedef float f32x4 __attribute__((ext_vector_type(4)));
typedef unsigned short u16x8 __attribute__((ext_vector_type(8)));

typedef const __attribute__((address_space(1))) unsigned int* gas_ptr;
typedef __attribute__((address_space(3))) unsigned int* las_ptr;

__device__ __forceinline__ unsigned short f2bf(float f) {
  unsigned int u = __float_as_uint(f);
  u += 0x7fffu + ((u >> 16) & 1u);  // RNE
  return (unsigned short)(u >> 16);
}

// fp32 -> bf16, one float4 per thread, grid-stride.
__global__ __launch_bounds__(256) void convert_bf16(const float* __restrict__ src,
                                                    unsigned short* __restrict__ dst, int n4) {
  int i = blockIdx.x * blockDim.x + threadIdx.x;
  const int stride = gridDim.x * blockDim.x;
  for (; i < n4; i += stride) {
    const float4 v = ((const float4*)src)[i];
    ushort4 o;
    o.x = f2bf(v.x); o.y = f2bf(v.y); o.z = f2bf(v.z); o.w = f2bf(v.w);
    ((ushort4*)dst)[i] = o;
  }
}

// Shared m97-style K-loop: C128x128 = A[128xK] * B[128xK]^T, K=512, lda=ldb=512,
// bf16 inputs, global_load_lds width-16 staging, 16x16x32 MFMA, 4 waves.
__device__ __forceinline__ void gemm_core(const unsigned short* __restrict__ A,
                                          const unsigned short* __restrict__ Bm,
                                          int m0, int n0,
                                          unsigned short* sA, unsigned short* sB,
                                          f32x4 acc[4][4]) {
  const int t = threadIdx.x;
  const int wave = t >> 6, lane = t & 63;
  const int wr = wave >> 1, wc = wave & 1;
  const int quad = lane >> 4, l16 = lane & 15;

  for (int k0 = 0; k0 < 512; k0 += 32) {
#pragma unroll
    for (int p = 0; p < 2; ++p) {
      const int ci = wave * 128 + p * 64 + lane;   // 16B chunk id, lane-contiguous
      const int row = ci >> 2, cg = ci & 3;
      const unsigned short* ga = A + (size_t)(m0 + row) * 512 + k0 + cg * 8;
      __builtin_amdgcn_global_load_lds((gas_ptr)(const void*)ga,
                                       (las_ptr)(void*)(sA + wave * 1024 + p * 512), 16, 0, 0);
      const unsigned short* gb = Bm + (size_t)(n0 + row) * 512 + k0 + cg * 8;
      __builtin_amdgcn_global_load_lds((gas_ptr)(const void*)gb,
                                       (las_ptr)(void*)(sB + wave * 1024 + p * 512), 16, 0, 0);
    }
    __syncthreads();
    bf16x8 af[4], bff[4];
#pragma unroll
    for (int i = 0; i < 4; ++i)
      af[i] = *(const bf16x8*)&sA[(wr * 64 + i * 16 + l16) * 32 + quad * 8];
#pragma unroll
    for (int j = 0; j < 4; ++j)
      bff[j] = *(const bf16x8*)&sB[(wc * 64 + j * 16 + l16) * 32 + quad * 8];
#pragma unroll
    for (int i = 0; i < 4; ++i)
#pragma unroll
      for (int j = 0; j < 4; ++j)
        acc[i][j] = __builtin_amdgcn_mfma_f32_16x16x32_bf16(af[i], bff[j], acc[i][j], 0, 0, 0);
    __syncthreads();
  }
}

// QKV projection: writes Q -> Qb[B*S][512], K -> Kb[B*S][512], V -> Vt[b][h][d][S] (transposed)
__global__ __launch_bounds__(256) void gemm_qkv(const unsigned short* __restrict__ xb,
                                                const unsigned short* __restrict__ wb,
                                                const float* __restrict__ bias,
                                                unsigned short* __restrict__ Qb,
                                                unsigned short* __restrict__ Kb,
                                                unsigned short* __restrict__ Vt) {
  __shared__ __align__(16) unsigned short sA[128 * 32];
  __shared__ __align__(16) unsigned short sB[128 * 32];
  f32x4 acc[4][4] = {};
  const int m0 = blockIdx.y * 128, n0 = blockIdx.x * 128;
  gemm_core(xb, wb, m0, n0, sA, sB, acc);

  const int t = threadIdx.x;
  const int wave = t >> 6, lane = t & 63;
  const int wr = wave >> 1, wc = wave & 1;
  const int quad = lane >> 4, l16 = lane & 15;
#pragma unroll
  for (int j = 0; j < 4; ++j) {
    const int n = n0 + wc * 64 + j * 16 + l16;
    const float bv = bias[n];
#pragma unroll
    for (int i = 0; i < 4; ++i) {
      const int mr = m0 + wr * 64 + i * 16 + quad * 4;
      if (n < DM) {
#pragma unroll
        for (int r = 0; r < 4; ++r)
          Qb[(size_t)(mr + r) * DM + n] = f2bf(acc[i][j][r] + bv);
      } else if (n < 2 * DM) {
#pragma unroll
        for (int r = 0; r < 4; ++r)
          Kb[(size_t)(mr + r) * DM + (n - DM)] = f2bf(acc[i][j][r] + bv);
      } else {
        const int d = n & 63, h = (n - 2 * DM) >> 6;
#pragma unroll
        for (int r = 0; r < 4; ++r) {
          const int m = mr + r;
          const int b = m >> 12, s = m & (S_LEN - 1);
          Vt[((size_t)((b * NH + h) * DH + d)) * S_LEN + s] = f2bf(acc[i][j][r] + bv);
        }
      }
    }
  }
}

// Output projection: C[m][n] fp32 = AO * wout^T + bias
__global__ __launch_bounds__(256) void gemm_out(const unsigned short* __restrict__ Ab,
                                                const unsigned short* __restrict__ wb,
                                                const float* __restrict__ bias,
                                                float* __restrict__ C) {
  __shared__ __align__(16) unsigned short sA[128 * 32];
  __shared__ __align__(16) unsigned short sB[128 * 32];
  f32x4 acc[4][4] = {};
  const int m0 = blockIdx.y * 128, n0 = blockIdx.x * 128;
  gemm_core(Ab, wb, m0, n0, sA, sB, acc);

  const int t = threadIdx.x;
  const int wave = t >> 6, lane = t & 63;
  const int wr = wave >> 1, wc = wave & 1;
  const int quad = lane >> 4, l16 = lane & 15;
#pragma unroll
  for (int j = 0; j < 4; ++j) {
    const int n = n0 + wc * 64 + j * 16 + l16;
    const float bv = bias[n];
#pragma unroll
    for (int i = 0; i < 4; ++i) {
      const int mr = m0 + wr * 64 + i * 16 + quad * 4;
#pragma unroll
      for (int r = 0; r < 4; ++r)
        C[(size_t)(mr + r) * DM + n] = acc[i][j][r] + bv;
    }
  }
}

// MFMA flash attention. WG(256)=4 waves per (b,h,64-query tile). Keys: 5 aligned
// 64-chunks [q0-256, q0+63], negatives skipped. Wave w owns q-rows w*16..w*16+15.
// LDS ld=72 bf16 -> all fragment reads 2-way bank aliasing (free).
__global__ __launch_bounds__(256) void attn_mfma(const unsigned short* __restrict__ Qb,
                                                 const unsigned short* __restrict__ Kb,
                                                 const unsigned short* __restrict__ Vt,
                                                 unsigned short* __restrict__ AO) {
  __shared__ __align__(16) unsigned short Qs[64 * 72];
  __shared__ __align__(16) unsigned short Ks[64 * 72];
  __shared__ __align__(16) unsigned short Vs[64 * 72];  // V^T chunk: [d][seq]
  __shared__ __align__(16) unsigned short Ps[64 * 72];
  const int t = threadIdx.x;
  const int wave = t >> 6, lane = t & 63;
  const int quad = lane >> 4, l16 = lane & 15;
  const int q0 = blockIdx.x * 64, h = blockIdx.y, b = blockIdx.z;

  // stage Q tile: 64 rows x 64 bf16 = 512 u16x8 chunks -> 2 per thread
#pragma unroll
  for (int s = 0; s < 2; ++s) {
    const int f = t + 256 * s;
    const int row = f >> 3, cg = f & 7;
    *(u16x8*)&Qs[row * 72 + cg * 8] =
        *(const u16x8*)(Qb + (size_t)(b * S_LEN + q0 + row) * DM + h * DH + cg * 8);
  }

  float m_[4], l_[4];
  f32x4 O[4] = {};
#pragma unroll
  for (int r = 0; r < 4; ++r) { m_[r] = -1e30f; l_[r] = 0.f; }

  for (int c = 0; c < 5; ++c) {
    const int c0 = q0 - WINDOW + c * 64;
    if (c0 < 0) continue;  // block-uniform
    __syncthreads();       // prior chunk's LDS reads done (also covers Q staging)
#pragma unroll
    for (int s = 0; s < 2; ++s) {
      const int f = t + 256 * s;
      const int row = f >> 3, cg = f & 7;
      *(u16x8*)&Ks[row * 72 + cg * 8] =
          *(const u16x8*)(Kb + (size_t)(b * S_LEN + c0 + row) * DM + h * DH + cg * 8);
      *(u16x8*)&Vs[row * 72 + cg * 8] =
          *(const u16x8*)(Vt + ((size_t)((b * NH + h) * DH + row)) * S_LEN + c0 + cg * 8);
    }
    __syncthreads();

    // S = Q K^T (rows = this wave's 16 q, cols = 64 keys)
    bf16x8 aq0 = *(const bf16x8*)&Qs[(wave * 16 + l16) * 72 + quad * 8];
    bf16x8 aq1 = *(const bf16x8*)&Qs[(wave * 16 + l16) * 72 + 32 + quad * 8];
    f32x4 sc[4];
#pragma unroll
    for (int nt = 0; nt < 4; ++nt) {
      bf16x8 bk0 = *(const bf16x8*)&Ks[(nt * 16 + l16) * 72 + quad * 8];
      bf16x8 bk1 = *(const bf16x8*)&Ks[(nt * 16 + l16) * 72 + 32 + quad * 8];
      f32x4 z = {};
      z = __builtin_amdgcn_mfma_f32_16x16x32_bf16(aq0, bk0, z, 0, 0, 0);
      sc[nt] = __builtin_amdgcn_mfma_f32_16x16x32_bf16(aq1, bk1, z, 0, 0, 0);
    }

    // mask + scale; C-layout: row = quad*4+reg, col = nt*16+l16
    float rmax[4];
#pragma unroll
    for (int r = 0; r < 4; ++r) rmax[r] = -1e30f;
#pragma unroll
    for (int nt = 0; nt < 4; ++nt) {
      const int j = c0 + nt * 16 + l16;
#pragma unroll
      for (int r = 0; r < 4; ++r) {
        const int i = q0 + wave * 16 + quad * 4 + r;
        const bool ok = (j <= i) && (j >= i - WINDOW);
        const float v = ok ? sc[nt][r] * 0.125f : -1e30f;
        sc[nt][r] = v;
        rmax[r] = fmaxf(rmax[r], v);
      }
    }
#pragma unroll
    for (int off = 1; off <= 8; off <<= 1)
#pragma unroll
      for (int r = 0; r < 4; ++r) rmax[r] = fmaxf(rmax[r], __shfl_xor(rmax[r], off));

    float alpha[4], csum[4];
#pragma unroll
    for (int r = 0; r < 4; ++r) {
      const float mn = fmaxf(m_[r], rmax[r]);
      alpha[r] = __expf(m_[r] - mn);
      m_[r] = mn;
      float su = 0.f;
#pragma unroll
      for (int nt = 0; nt < 4; ++nt) {
        const float p = __expf(sc[nt][r] - mn);
        sc[nt][r] = p;
        su += p;
      }
      csum[r] = su;
    }
#pragma unroll
    for (int off = 1; off <= 8; off <<= 1)
#pragma unroll
      for (int r = 0; r < 4; ++r) csum[r] += __shfl_xor(csum[r], off);
#pragma unroll
    for (int r = 0; r < 4; ++r) l_[r] = l_[r] * alpha[r] + csum[r];

    // P -> LDS (C-layout to A-layout), own wave's rows only: no barrier needed
#pragma unroll
    for (int nt = 0; nt < 4; ++nt)
#pragma unroll
      for (int r = 0; r < 4; ++r)
        Ps[(wave * 16 + quad * 4 + r) * 72 + nt * 16 + l16] = f2bf(sc[nt][r]);

    // O = diag(alpha) O + P V  (B-frag[n=d][k=seq] = V^T rows = Vs rows)
    bf16x8 ap0 = *(const bf16x8*)&Ps[(wave * 16 + l16) * 72 + quad * 8];
    bf16x8 ap1 = *(const bf16x8*)&Ps[(wave * 16 + l16) * 72 + 32 + quad * 8];
#pragma unroll
    for (int nt = 0; nt < 4; ++nt) {
#pragma unroll
      for (int r = 0; r < 4; ++r) O[nt][r] *= alpha[r];
      bf16x8 bv0 = *(const bf16x8*)&Vs[(nt * 16 + l16) * 72 + quad * 8];
      bf16x8 bv1 = *(const bf16x8*)&Vs[(nt * 16 + l16) * 72 + 32 + quad * 8];
      O[nt] = __builtin_amdgcn_mfma_f32_16x16x32_bf16(ap0, bv0, O[nt], 0, 0, 0);
      O[nt] = __builtin_amdgcn_mfma_f32_16x16x32_bf16(ap1, bv1, O[nt], 0, 0, 0);
    }
  }

#pragma unroll
  for (int r = 0; r < 4; ++r) l_[r] = 1.f / l_[r];
#pragma unroll
  for (int nt = 0; nt < 4; ++nt) {
    const int col = h * DH + nt * 16 + l16;
#pragma unroll
    for (int r = 0; r < 4; ++r) {
      const int m = b * S_LEN + q0 + wave * 16 + quad * 4 + r;
      AO[(size_t)m * DM + col] = f2bf(O[nt][r] * l_[r]);
    }
  }
}

extern "C" void kernel_launch(void* const* d_in, const int* in_sizes, int n_in,
                              void* d_out, int out_size, void* d_ws, size_t ws_size,
                              hipStream_t stream) {
  const float* x = (const float*)d_in[0];
  const float* qkv_w = (const float*)d_in[1];
  const float* qkv_b = (const float*)d_in[2];
  const float* out_w = (const float*)d_in[3];
  const float* out_b = (const float*)d_in[4];
  float* out = (float*)d_out;

  const int M = BATCH * S_LEN;  // 8192
  unsigned short* ws = (unsigned short*)d_ws;
  unsigned short* xb   = ws;                      // 8192*512
  unsigned short* wqkv = xb + (size_t)M * DM;     // 1536*512
  unsigned short* wout = wqkv + 3 * DM * DM;      // 512*512
  unsigned short* Qb   = wout + DM * DM;          // 8192*512
  unsigned short* Kb   = Qb + (size_t)M * DM;     // 8192*512
  unsigned short* Vt   = Kb + (size_t)M * DM;     // 2*8*64*4096
  unsigned short* AO   = Vt + (size_t)M * DM;     // 8192*512

  convert_bf16<<<1024, 256, 0, stream>>>(x, xb, M * DM / 4);
  convert_bf16<<<768, 256, 0, stream>>>(qkv_w, wqkv, 3 * DM * DM / 4);
  convert_bf16<<<256, 256, 0, stream>>>(out_w, wout, DM * DM / 4);

  gemm_qkv<<<dim3(3 * DM / 128, M / 128), 256, 0, stream>>>(xb, wqkv, qkv_b, Qb, Kb, Vt);

  attn_mfma<<<dim3(S_LEN / 64, NH, BATCH), 256, 0, stream>>>(Qb, Kb, Vt, AO);

  gemm_out<<<dim3(DM / 128, M / 128), 256, 0, stream>>>(AO, wout, out_b, out);
}

// Round 5
// 149.687 us; speedup vs baseline: 14.2113x; 1.0082x over previous
//
#include <hip/hip_runtime.h>

#define S_LEN 4096
#define BATCH 2
#define DM 512
#define NH 8
#define DH 64
#define WINDOW 256

typedef __bf16 bf16x8 __attribute__((ext_vector_type(8)));
typedef float f32x4 __attribute__((ext_vector_type(4)));
typedef unsigned short u16x8 __attribute__((ext_vector_type(8)));

typedef const __attribute__((address_space(1))) unsigned int* gas_ptr;
typedef __attribute__((address_space(3))) unsigned int* las_ptr;

#define SCALE_LOG2E 0.1803368801111204f  // 0.125 * log2(e)

__device__ __forceinline__ unsigned short f2bf(float f) {
  unsigned int u = __float_as_uint(f);
  u += 0x7fffu + ((u >> 16) & 1u);  // RNE
  return (unsigned short)(u >> 16);
}

// One fused fp32->bf16 convert for x, qkv_w, out_w (contiguous dest regions).
#define N4_X (8192 * 512 / 4)
#define N4_QW (1536 * 512 / 4)
#define N4_OW (512 * 512 / 4)
__global__ __launch_bounds__(256) void convert_all(const float* __restrict__ x,
                                                   const float* __restrict__ qw,
                                                   const float* __restrict__ ow,
                                                   unsigned short* __restrict__ dst) {
  const int i = blockIdx.x * blockDim.x + threadIdx.x;  // exact grid, one float4 each
  const float4* src;
  int off;
  if (i < N4_X) { src = (const float4*)x; off = 0; }
  else if (i < N4_X + N4_QW) { src = (const float4*)qw; off = N4_X; }
  else { src = (const float4*)ow; off = N4_X + N4_QW; }
  const float4 v = src[i - off];
  ushort4 o;
  o.x = f2bf(v.x); o.y = f2bf(v.y); o.z = f2bf(v.z); o.w = f2bf(v.w);
  ((ushort4*)dst)[i] = o;
}

// m97-style K-loop: C128x128 = A[128xK] * B[128xK]^T, K=512, lda=ldb=512,
// bf16 inputs, global_load_lds width-16 staging, 16x16x32 MFMA, 4 waves.
__device__ __forceinline__ void gemm_core(const unsigned short* __restrict__ A,
                                          const unsigned short* __restrict__ Bm,
                                          int m0, int n0,
                                          unsigned short* sA, unsigned short* sB,
                                          f32x4 acc[4][4]) {
  const int t = threadIdx.x;
  const int wave = t >> 6, lane = t & 63;
  const int wr = wave >> 1, wc = wave & 1;
  const int quad = lane >> 4, l16 = lane & 15;

  for (int k0 = 0; k0 < 512; k0 += 32) {
#pragma unroll
    for (int p = 0; p < 2; ++p) {
      const int ci = wave * 128 + p * 64 + lane;   // 16B chunk id, lane-contiguous
      const int row = ci >> 2, cg = ci & 3;
      const unsigned short* ga = A + (size_t)(m0 + row) * 512 + k0 + cg * 8;
      __builtin_amdgcn_global_load_lds((gas_ptr)(const void*)ga,
                                       (las_ptr)(void*)(sA + wave * 1024 + p * 512), 16, 0, 0);
      const unsigned short* gb = Bm + (size_t)(n0 + row) * 512 + k0 + cg * 8;
      __builtin_amdgcn_global_load_lds((gas_ptr)(const void*)gb,
                                       (las_ptr)(void*)(sB + wave * 1024 + p * 512), 16, 0, 0);
    }
    __syncthreads();
    bf16x8 af[4], bff[4];
#pragma unroll
    for (int i = 0; i < 4; ++i)
      af[i] = *(const bf16x8*)&sA[(wr * 64 + i * 16 + l16) * 32 + quad * 8];
#pragma unroll
    for (int j = 0; j < 4; ++j)
      bff[j] = *(const bf16x8*)&sB[(wc * 64 + j * 16 + l16) * 32 + quad * 8];
#pragma unroll
    for (int i = 0; i < 4; ++i)
#pragma unroll
      for (int j = 0; j < 4; ++j)
        acc[i][j] = __builtin_amdgcn_mfma_f32_16x16x32_bf16(af[i], bff[j], acc[i][j], 0, 0, 0);
    __syncthreads();
  }
}

// QKV projection: Q -> Qb[B*S][512], K -> Kb[B*S][512], V -> Vt[b][h][d][S] (transposed)
__global__ __launch_bounds__(256) void gemm_qkv(const unsigned short* __restrict__ xb,
                                                const unsigned short* __restrict__ wb,
                                                const float* __restrict__ bias,
                                                unsigned short* __restrict__ Qb,
                                                unsigned short* __restrict__ Kb,
                                                unsigned short* __restrict__ Vt) {
  __shared__ __align__(16) unsigned short sA[128 * 32];
  __shared__ __align__(16) unsigned short sB[128 * 32];
  f32x4 acc[4][4] = {};
  const int m0 = blockIdx.y * 128, n0 = blockIdx.x * 128;
  gemm_core(xb, wb, m0, n0, sA, sB, acc);

  const int t = threadIdx.x;
  const int wave = t >> 6, lane = t & 63;
  const int wr = wave >> 1, wc = wave & 1;
  const int quad = lane >> 4, l16 = lane & 15;
#pragma unroll
  for (int j = 0; j < 4; ++j) {
    const int n = n0 + wc * 64 + j * 16 + l16;
    const float bv = bias[n];
#pragma unroll
    for (int i = 0; i < 4; ++i) {
      const int mr = m0 + wr * 64 + i * 16 + quad * 4;
      if (n < DM) {
#pragma unroll
        for (int r = 0; r < 4; ++r)
          Qb[(size_t)(mr + r) * DM + n] = f2bf(acc[i][j][r] + bv);
      } else if (n < 2 * DM) {
#pragma unroll
        for (int r = 0; r < 4; ++r)
          Kb[(size_t)(mr + r) * DM + (n - DM)] = f2bf(acc[i][j][r] + bv);
      } else {
        const int d = n & 63, h = (n - 2 * DM) >> 6;
#pragma unroll
        for (int r = 0; r < 4; ++r) {
          const int m = mr + r;
          const int b = m >> 12, s = m & (S_LEN - 1);
          Vt[((size_t)((b * NH + h) * DH + d)) * S_LEN + s] = f2bf(acc[i][j][r] + bv);
        }
      }
    }
  }
}

// Output projection: C fp32 = AO * wout^T + bias
__global__ __launch_bounds__(256) void gemm_out(const unsigned short* __restrict__ Ab,
                                                const unsigned short* __restrict__ wb,
                                                const float* __restrict__ bias,
                                                float* __restrict__ C) {
  __shared__ __align__(16) unsigned short sA[128 * 32];
  __shared__ __align__(16) unsigned short sB[128 * 32];
  f32x4 acc[4][4] = {};
  const int m0 = blockIdx.y * 128, n0 = blockIdx.x * 128;
  gemm_core(Ab, wb, m0, n0, sA, sB, acc);

  const int t = threadIdx.x;
  const int wave = t >> 6, lane = t & 63;
  const int wr = wave >> 1, wc = wave & 1;
  const int quad = lane >> 4, l16 = lane & 15;
#pragma unroll
  for (int j = 0; j < 4; ++j) {
    const int n = n0 + wc * 64 + j * 16 + l16;
    const float bv = bias[n];
#pragma unroll
    for (int i = 0; i < 4; ++i) {
      const int mr = m0 + wr * 64 + i * 16 + quad * 4;
#pragma unroll
      for (int r = 0; r < 4; ++r)
        C[(size_t)(mr + r) * DM + n] = acc[i][j][r] + bv;
    }
  }
}

// MFMA flash attention, register-double-buffered K/V prefetch, compile-time
// mask specialization (chunks 1-3 are provably unmasked), exp2-domain softmax.
// WG(256)=4 waves per (b,h,64-query tile); 5 aligned 64-key chunks.
__global__ __launch_bounds__(256) void attn_mfma(const unsigned short* __restrict__ Qb,
                                                 const unsigned short* __restrict__ Kb,
                                                 const unsigned short* __restrict__ Vt,
                                                 unsigned short* __restrict__ AO) {
  __shared__ __align__(16) unsigned short Qs[64 * 72];
  __shared__ __align__(16) unsigned short Ks[64 * 72];
  __shared__ __align__(16) unsigned short Vs[64 * 72];  // V^T chunk: [d][seq]
  __shared__ __align__(16) unsigned short Ps[64 * 72];
  const int t = threadIdx.x;
  const int wave = t >> 6, lane = t & 63;
  const int quad = lane >> 4, l16 = lane & 15;
  const int q0 = blockIdx.x * 64, h = blockIdx.y, b = blockIdx.z;

  const unsigned short* Kbase = Kb + (size_t)b * S_LEN * DM + h * DH;
  const unsigned short* Vbase = Vt + (size_t)((b * NH + h) * DH) * S_LEN;

  // stage Q tile: 512 u16x8 chunks -> 2 per thread (LDS write, visible after
  // the first executed chunk's second barrier)
#pragma unroll
  for (int s = 0; s < 2; ++s) {
    const int f = t + 256 * s;
    const int row = f >> 3, cg = f & 7;
    *(u16x8*)&Qs[row * 72 + cg * 8] =
        *(const u16x8*)(Qb + (size_t)(b * S_LEN + q0 + row) * DM + h * DH + cg * 8);
  }

  const int first = (q0 >= WINDOW) ? 0 : (4 - blockIdx.x);  // first valid chunk

  u16x8 kbuf[2][2], vbuf[2][2];
#define LOAD_CHUNK(c0, p)                                                      \
  do {                                                                         \
    _Pragma("unroll") for (int s = 0; s < 2; ++s) {                            \
      const int f = t + 256 * s;                                               \
      const int row = f >> 3, c8 = f & 7;                                      \
      kbuf[p][s] = *(const u16x8*)(Kbase + (size_t)((c0) + row) * DM + c8 * 8);\
      vbuf[p][s] = *(const u16x8*)(Vbase + (size_t)row * S_LEN + (c0) + c8 * 8);\
    }                                                                          \
  } while (0)

  // prologue: load first valid chunk (block-uniform branch)
#pragma unroll
  for (int c = 0; c < 5; ++c)
    if (c == first) LOAD_CHUNK(q0 - WINDOW + c * 64, c & 1);

  float m_[4], l_[4];
  f32x4 O[4] = {};
#pragma unroll
  for (int r = 0; r < 4; ++r) { m_[r] = -1e30f; l_[r] = 0.f; }

#pragma unroll
  for (int c = 0; c < 5; ++c) {
    if (c < first) continue;  // block-uniform
    const int c0 = q0 - WINDOW + c * 64;
    __syncthreads();  // prior chunk's LDS reads complete before overwrite
    // VGPR -> LDS for this chunk
#pragma unroll
    for (int s = 0; s < 2; ++s) {
      const int f = t + 256 * s;
      const int row = f >> 3, c8 = f & 7;
      *(u16x8*)&Ks[row * 72 + c8 * 8] = kbuf[c & 1][s];
      *(u16x8*)&Vs[row * 72 + c8 * 8] = vbuf[c & 1][s];
    }
    // prefetch next chunk while this one computes
    if (c < 4) LOAD_CHUNK(c0 + 64, (c + 1) & 1);
    __syncthreads();

    // S = Q K^T (this wave's 16 q-rows x 64 keys)
    bf16x8 aq0 = *(const bf16x8*)&Qs[(wave * 16 + l16) * 72 + quad * 8];
    bf16x8 aq1 = *(const bf16x8*)&Qs[(wave * 16 + l16) * 72 + 32 + quad * 8];
    f32x4 sc[4];
#pragma unroll
    for (int nt = 0; nt < 4; ++nt) {
      bf16x8 bk0 = *(const bf16x8*)&Ks[(nt * 16 + l16) * 72 + quad * 8];
      bf16x8 bk1 = *(const bf16x8*)&Ks[(nt * 16 + l16) * 72 + 32 + quad * 8];
      f32x4 z = {};
      z = __builtin_amdgcn_mfma_f32_16x16x32_bf16(aq0, bk0, z, 0, 0, 0);
      sc[nt] = __builtin_amdgcn_mfma_f32_16x16x32_bf16(aq1, bk1, z, 0, 0, 0);
    }

    // scale into log2 domain; masks only on boundary chunks (c compile-time):
    // c==0: valid iff jj >= ii; c==4: valid iff jj <= ii; c 1..3: all valid.
    float rmax[4];
#pragma unroll
    for (int r = 0; r < 4; ++r) rmax[r] = -1e30f;
#pragma unroll
    for (int nt = 0; nt < 4; ++nt) {
      const int jj = nt * 16 + l16;
#pragma unroll
      for (int r = 0; r < 4; ++r) {
        const int ii = wave * 16 + quad * 4 + r;
        float v = sc[nt][r] * SCALE_LOG2E;
        if (c == 0) v = (jj >= ii) ? v : -1e30f;
        if (c == 4) v = (jj <= ii) ? v : -1e30f;
        sc[nt][r] = v;
        rmax[r] = fmaxf(rmax[r], v);
      }
    }
#pragma unroll
    for (int off = 1; off <= 8; off <<= 1)
#pragma unroll
      for (int r = 0; r < 4; ++r) rmax[r] = fmaxf(rmax[r], __shfl_xor(rmax[r], off));

    float alpha[4], csum[4];
#pragma unroll
    for (int r = 0; r < 4; ++r) {
      const float mn = fmaxf(m_[r], rmax[r]);
      alpha[r] = exp2f(m_[r] - mn);
      m_[r] = mn;
      float su = 0.f;
#pragma unroll
      for (int nt = 0; nt < 4; ++nt) {
        const float p = exp2f(sc[nt][r] - mn);
        sc[nt][r] = p;
        su += p;
      }
      csum[r] = su;
    }
#pragma unroll
    for (int off = 1; off <= 8; off <<= 1)
#pragma unroll
      for (int r = 0; r < 4; ++r) csum[r] += __shfl_xor(csum[r], off);
#pragma unroll
    for (int r = 0; r < 4; ++r) l_[r] = l_[r] * alpha[r] + csum[r];

    // P: C-layout -> A-layout via LDS, own wave's rows only (no barrier)
#pragma unroll
    for (int nt = 0; nt < 4; ++nt)
#pragma unroll
      for (int r = 0; r < 4; ++r)
        Ps[(wave * 16 + quad * 4 + r) * 72 + nt * 16 + l16] = f2bf(sc[nt][r]);

    // O = diag(alpha) O + P V
    bf16x8 ap0 = *(const bf16x8*)&Ps[(wave * 16 + l16) * 72 + quad * 8];
    bf16x8 ap1 = *(const bf16x8*)&Ps[(wave * 16 + l16) * 72 + 32 + quad * 8];
#pragma unroll
    for (int nt = 0; nt < 4; ++nt) {
#pragma unroll
      for (int r = 0; r < 4; ++r) O[nt][r] *= alpha[r];
      bf16x8 bv0 = *(const bf16x8*)&Vs[(nt * 16 + l16) * 72 + quad * 8];
      bf16x8 bv1 = *(const bf16x8*)&Vs[(nt * 16 + l16) * 72 + 32 + quad * 8];
      O[nt] = __builtin_amdgcn_mfma_f32_16x16x32_bf16(ap0, bv0, O[nt], 0, 0, 0);
      O[nt] = __builtin_amdgcn_mfma_f32_16x16x32_bf16(ap1, bv1, O[nt], 0, 0, 0);
    }
  }

#pragma unroll
  for (int r = 0; r < 4; ++r) l_[r] = 1.f / l_[r];
#pragma unroll
  for (int nt = 0; nt < 4; ++nt) {
    const int col = h * DH + nt * 16 + l16;
#pragma unroll
    for (int r = 0; r < 4; ++r) {
      const int m = b * S_LEN + q0 + wave * 16 + quad * 4 + r;
      AO[(size_t)m * DM + col] = f2bf(O[nt][r] * l_[r]);
    }
  }
}

extern "C" void kernel_launch(void* const* d_in, const int* in_sizes, int n_in,
                              void* d_out, int out_size, void* d_ws, size_t ws_size,
                              hipStream_t stream) {
  const float* x = (const float*)d_in[0];
  const float* qkv_w = (const float*)d_in[1];
  const float* qkv_b = (const float*)d_in[2];
  const float* out_w = (const float*)d_in[3];
  const float* out_b = (const float*)d_in[4];
  float* out = (float*)d_out;

  const int M = BATCH * S_LEN;  // 8192
  unsigned short* ws = (unsigned short*)d_ws;
  unsigned short* xb   = ws;                      // 8192*512
  unsigned short* wqkv = xb + (size_t)M * DM;     // 1536*512
  unsigned short* wout = wqkv + 3 * DM * DM;      // 512*512
  unsigned short* Qb   = wout + DM * DM;          // 8192*512
  unsigned short* Kb   = Qb + (size_t)M * DM;     // 8192*512
  unsigned short* Vt   = Kb + (size_t)M * DM;     // 2*8*64*4096
  unsigned short* AO   = Vt + (size_t)M * DM;     // 8192*512

  convert_all<<<(N4_X + N4_QW + N4_OW) / 256, 256, 0, stream>>>(x, qkv_w, out_w, xb);

  gemm_qkv<<<dim3(3 * DM / 128, M / 128), 256, 0, stream>>>(xb, wqkv, qkv_b, Qb, Kb, Vt);

  attn_mfma<<<dim3(S_LEN / 64, NH, BATCH), 256, 0, stream>>>(Qb, Kb, Vt, AO);

  gemm_out<<<dim3(DM / 128, M / 128), 256, 0, stream>>>(AO, wout, out_b, out);
}